// Round 2
// baseline (141.676 us; speedup 1.0000x reference)
//
#include <hip/hip_runtime.h>
#include <cmath>

#define DD   10
#define FF   32
#define OUTN 32
#define BVPB 8      // (b,v) pairs per block = one per 32-lane half-wave
#define NT   256

// Kernel 1: summed[b,v,f] = sum_d inputs[b,v,d,f]  (float4-vectorized)
__global__ __launch_bounds__(NT) void sum_d4_kernel(
    const float4* __restrict__ in, float4* __restrict__ out, int n4) {
    int idx = blockIdx.x * NT + threadIdx.x;
    if (idx >= n4) return;
    int f4 = idx & 7;          // FF/4 = 8 float4 per row
    int bv = idx >> 3;
    const float4* p = in + (size_t)bv * (DD * 8) + f4;
    float4 s = p[0];
#pragma unroll
    for (int d = 1; d < DD; ++d) {
        float4 v = p[d * 8];
        s.x += v.x; s.y += v.y; s.z += v.z; s.w += v.w;
    }
    out[idx] = s;
}

// Kernel 2: one (b,v) per 32-lane group; lane = output channel o.
__global__ __launch_bounds__(NT) void gat_kernel(
    const float* __restrict__ summed,
    const float* __restrict__ init,
    const float* __restrict__ mask,
    const float* __restrict__ Wk,
    const float* __restrict__ Wb,
    const float* __restrict__ Ak,
    const int* __restrict__ adj,
    const int* __restrict__ mask_index_p,
    float* __restrict__ out,
    int B, int V) {
    __shared__ float sW[FF * OUTN];          // 4 KB, staged once
    __shared__ float sGI[BVPB][DD][FF];      // 10 KB, wave-local halves

    const int t  = threadIdx.x;
    const int o  = t & 31;                   // output channel / feature lane
    const int p  = t >> 5;                   // pair slot 0..7 (wave*2 + half)
    const int bv0 = blockIdx.x * BVPB;
    const int bv  = bv0 + p;
    const int BV  = B * V;
    const int mask_index = *mask_index_p;

    for (int i = t; i < FF * OUTN; i += NT) sW[i] = Wk[i];
    __syncthreads();

    // W column for this lane's o, in registers (static-indexed only)
    float Wc[FF];
#pragma unroll
    for (int f = 0; f < FF; ++f) Wc[f] = sW[f * OUTN + o];  // bank=o, 2-way free
    const float bias_o = Wb[o];
    const float a_o    = Ak[o];

    const bool valid = bv < BV;
    const int bvc = valid ? bv : BV - 1;
    const int b = bvc / V;
    const float* initp = init + (size_t)bvc * (DD * FF);
    const float* maskp = mask + (size_t)bvc * DD;
    const int*   adjp  = adj  + (size_t)bvc * DD;

    // phase 1: gi[d][f] = zm*(gather + init)  -> LDS (coalesced global loads)
    float zm[DD];
#pragma unroll
    for (int j = 0; j < DD; ++j) {
        float m = maskp[j];                  // uniform addr per half
        int   a = adjp[j];
        zm[j] = 1.f - m;
        float g = 0.f;
        if (a != mask_index) {
            int ac = a < 0 ? 0 : (a >= V ? V - 1 : a);   // JAX clamp semantics
            g = summed[((size_t)b * V + ac) * FF + o];   // coalesced 128B/half
        }
        sGI[p][j][o] = zm[j] * (g + initp[j * FF + o]);
    }
    __syncthreads();

    // phase 2: T[d] = zm * relu(gi . W[:,o] + bias) — b128 broadcast reads
    float T[DD];
#pragma unroll
    for (int j = 0; j < DD; ++j) T[j] = bias_o;
    const float4* g4 = (const float4*)(&sGI[p][0][0]);
#pragma unroll
    for (int j = 0; j < DD; ++j) {
#pragma unroll
        for (int q = 0; q < FF / 4; ++q) {
            float4 g = g4[j * (FF / 4) + q];
            T[j] = fmaf(g.x, Wc[q * 4 + 0], T[j]);
            T[j] = fmaf(g.y, Wc[q * 4 + 1], T[j]);
            T[j] = fmaf(g.z, Wc[q * 4 + 2], T[j]);
            T[j] = fmaf(g.w, Wc[q * 4 + 3], T[j]);
        }
        T[j] = fmaxf(T[j], 0.f) * zm[j];
    }

    // phase 3: aw[d] = sum_o T[d][o]*a[o] via shfl-xor reduce (within 32-group)
    float aw[DD];
#pragma unroll
    for (int j = 0; j < DD; ++j) {
        float v = T[j] * a_o;
        v += __shfl_xor(v, 16);
        v += __shfl_xor(v, 8);
        v += __shfl_xor(v, 4);
        v += __shfl_xor(v, 2);
        v += __shfl_xor(v, 1);
        aw[j] = v - 1e7f * (1.f - zm[j]);
    }

    // phase 4: softmax over D in registers (all lanes redundantly)
    float mx = aw[0];
#pragma unroll
    for (int j = 1; j < DD; ++j) mx = fmaxf(mx, aw[j]);
    float ssum = 0.f;
    float e[DD];
#pragma unroll
    for (int j = 0; j < DD; ++j) { e[j] = __expf(aw[j] - mx); ssum += e[j]; }
    const float inv = 1.f / ssum;

    // phase 5: out = coef * T, coalesced stores
    if (valid) {
        float* outp = out + (size_t)bv * (DD * OUTN);
#pragma unroll
        for (int j = 0; j < DD; ++j) outp[j * OUTN + o] = (e[j] * inv) * T[j];
    }
}

extern "C" void kernel_launch(void* const* d_in, const int* in_sizes, int n_in,
                              void* d_out, int out_size, void* d_ws, size_t ws_size,
                              hipStream_t stream) {
    const float* inputs = (const float*)d_in[0];
    const float* init   = (const float*)d_in[1];
    const float* mask   = (const float*)d_in[2];
    const float* Wk     = (const float*)d_in[3];
    const float* Wb     = (const float*)d_in[4];
    const float* Ak     = (const float*)d_in[5];
    const int*   adj    = (const int*)d_in[6];
    const int*   mip    = (const int*)d_in[7];

    const int B   = 4;
    const int BVD = in_sizes[2];          // B*V*D
    const int V   = BVD / (B * DD);
    const int BV  = B * V;

    float* summed = (float*)d_ws;         // B*V*FF floats = 10.24 MB
    int n4 = BV * (FF / 4);
    hipLaunchKernelGGL(sum_d4_kernel, dim3((n4 + NT - 1) / NT), dim3(NT), 0, stream,
                       (const float4*)inputs, (float4*)summed, n4);
    hipLaunchKernelGGL(gat_kernel, dim3((BV + BVPB - 1) / BVPB), dim3(NT), 0, stream,
                       summed, init, mask, Wk, Wb, Ak, adj, mip, (float*)d_out, B, V);
}

// Round 4
// 90.291 us; speedup vs baseline: 1.5691x; 1.5691x over previous
//
#include <hip/hip_runtime.h>
#include <cmath>

#define DD   10
#define FF   32
#define OUTN 32
#define BVPB 8      // (b,v) pairs per block = one per 32-lane half-wave
#define NT   256

typedef float f32x4 __attribute__((ext_vector_type(4)));

// Kernel 1: summed[b,v,f] = sum_d inputs[b,v,d,f]  (float4, nt loads)
__global__ __launch_bounds__(NT) void sum_d4_kernel(
    const f32x4* __restrict__ in, f32x4* __restrict__ out, int n4) {
    int idx = blockIdx.x * NT + threadIdx.x;
    if (idx >= n4) return;
    int f4 = idx & 7;          // FF/4 = 8 float4 per row
    int bv = idx >> 3;
    const f32x4* p = in + (size_t)bv * (DD * 8) + f4;
    f32x4 s = __builtin_nontemporal_load(p);
#pragma unroll
    for (int d = 1; d < DD; ++d) {
        f32x4 v = __builtin_nontemporal_load(p + d * 8);
        s += v;
    }
    out[idx] = s;               // re-read by gat: keep cacheable
}

// Kernel 2: one (b,v) per 32-lane group; lane = output channel o.
// No barriers: sGI is wave-local; W read per-lane from global (L1-hot).
__global__ __launch_bounds__(NT) void gat_kernel(
    const float* __restrict__ summed,
    const float* __restrict__ init,
    const float* __restrict__ mask,
    const float* __restrict__ Wk,
    const float* __restrict__ Wb,
    const float* __restrict__ Ak,
    const int* __restrict__ adj,
    const int* __restrict__ mask_index_p,
    float* __restrict__ out,
    int B, int V) {
    __shared__ float sGI[BVPB][DD][FF];      // 10 KB, wave-local halves

    const int t  = threadIdx.x;
    const int o  = t & 31;                   // output channel / feature lane
    const int p  = t >> 5;                   // pair slot 0..7
    const int BV = B * V;
    int bv = blockIdx.x * BVPB + p;
    const bool valid = bv < BV;
    if (!valid) bv = BV - 1;
    const int b = bv / V;
    const int mask_index = *mask_index_p;

    const float* initp = init + (size_t)bv * (DD * FF);
    const float* maskp = mask + (size_t)bv * DD;
    const int*   adjp  = adj  + (size_t)bv * DD;
    const float* sumb  = summed + (size_t)b * V * FF;

    // ---- load adj + mask rows (broadcast within group, L1 line) ----
    int   a[DD];
    float zm[DD];
#pragma unroll
    for (int j = 0; j < DD; ++j) { a[j] = adjp[j]; zm[j] = 1.f - maskp[j]; }

    // ---- unconditional gathers + init loads: 20 loads in flight ----
    float g[DD], ini[DD];
#pragma unroll
    for (int j = 0; j < DD; ++j) {
        int ac = a[j] < 0 ? 0 : (a[j] >= V ? V - 1 : a[j]);  // JAX clamp
        g[j]   = sumb[(size_t)ac * FF + o];                  // coalesced 128B/half
        ini[j] = __builtin_nontemporal_load(initp + j * FF + o);
    }

    // ---- W column + bias + a for this lane (coalesced, L1-hot) ----
    float Wc[FF];
#pragma unroll
    for (int f = 0; f < FF; ++f) Wc[f] = Wk[f * OUTN + o];
    const float bias_o = Wb[o];
    const float a_o    = Ak[o];

    // ---- gi -> LDS (select masked-out neighbors to 0; no branch) ----
#pragma unroll
    for (int j = 0; j < DD; ++j) {
        float gv = (a[j] == mask_index) ? 0.f : g[j];
        sGI[p][j][o] = zm[j] * (gv + ini[j]);
    }
    // wave-local LDS: compiler emits lgkmcnt wait, no barrier needed

    // ---- dense F->OUT + relu, gi via b128 broadcast reads ----
    float T[DD];
#pragma unroll
    for (int j = 0; j < DD; ++j) T[j] = bias_o;
    const f32x4* g4 = (const f32x4*)(&sGI[p][0][0]);
#pragma unroll
    for (int j = 0; j < DD; ++j) {
#pragma unroll
        for (int q = 0; q < FF / 4; ++q) {
            f32x4 gv = g4[j * (FF / 4) + q];
            T[j] = fmaf(gv.x, Wc[q * 4 + 0], T[j]);
            T[j] = fmaf(gv.y, Wc[q * 4 + 1], T[j]);
            T[j] = fmaf(gv.z, Wc[q * 4 + 2], T[j]);
            T[j] = fmaf(gv.w, Wc[q * 4 + 3], T[j]);
        }
        T[j] = fmaxf(T[j], 0.f) * zm[j];
    }

    // ---- attn dot: shfl-xor reduce within the 32-group ----
    float aw[DD];
#pragma unroll
    for (int j = 0; j < DD; ++j) {
        float v = T[j] * a_o;
        v += __shfl_xor(v, 16);
        v += __shfl_xor(v, 8);
        v += __shfl_xor(v, 4);
        v += __shfl_xor(v, 2);
        v += __shfl_xor(v, 1);
        aw[j] = v - 1e7f * (1.f - zm[j]);
    }

    // ---- softmax over D in registers (redundant per lane) ----
    float mx = aw[0];
#pragma unroll
    for (int j = 1; j < DD; ++j) mx = fmaxf(mx, aw[j]);
    float ssum = 0.f;
    float e[DD];
#pragma unroll
    for (int j = 0; j < DD; ++j) { e[j] = __expf(aw[j] - mx); ssum += e[j]; }
    const float inv = 1.f / ssum;

    // ---- out = coef * T, coalesced nontemporal stores ----
    if (valid) {
        float* outp = out + (size_t)bv * (DD * OUTN);
#pragma unroll
        for (int j = 0; j < DD; ++j)
            __builtin_nontemporal_store((e[j] * inv) * T[j], outp + j * OUTN + o);
    }
}

extern "C" void kernel_launch(void* const* d_in, const int* in_sizes, int n_in,
                              void* d_out, int out_size, void* d_ws, size_t ws_size,
                              hipStream_t stream) {
    const float* inputs = (const float*)d_in[0];
    const float* init   = (const float*)d_in[1];
    const float* mask   = (const float*)d_in[2];
    const float* Wk     = (const float*)d_in[3];
    const float* Wb     = (const float*)d_in[4];
    const float* Ak     = (const float*)d_in[5];
    const int*   adj    = (const int*)d_in[6];
    const int*   mip    = (const int*)d_in[7];

    const int B   = 4;
    const int BVD = in_sizes[2];          // B*V*D
    const int V   = BVD / (B * DD);
    const int BV  = B * V;

    float* summed = (float*)d_ws;         // B*V*FF floats = 10.24 MB
    int n4 = BV * (FF / 4);
    hipLaunchKernelGGL(sum_d4_kernel, dim3((n4 + NT - 1) / NT), dim3(NT), 0, stream,
                       (const f32x4*)inputs, (f32x4*)summed, n4);
    hipLaunchKernelGGL(gat_kernel, dim3((BV + BVPB - 1) / BVPB), dim3(NT), 0, stream,
                       summed, init, mask, Wk, Wb, Ak, adj, mip, (float*)d_out, B, V);
}